// Round 4
// baseline (121.154 us; speedup 1.0000x reference)
//
#include <hip/hip_runtime.h>

// HilbertSchmidtVQ — straight-through estimator forward pass.
//
// reference: out = rho_flat + (quantized - stop_gradient(quantized))
// Forward value == rho_flat bitwise (quantized cancels itself exactly);
// argmin/gather only affects gradients, never evaluated here. Optimal
// kernel = 64 MiB fp32 copy (128 MiB HBM traffic, ~20 us at 6.3 TB/s).
//
// R2: reported dur_us (111.7) dominated by ~90 us harness poison resets
// (256 MiB fills at 41 us top the profile); our copy is < 41 us.
// R3 fix: __builtin_nontemporal_* rejects HIP_vector_type float4 — use a
// clang ext_vector_type(4) float alias instead (same 16 B layout).
//
// n4 = 4,194,304 float4. 4096 blocks x 256 thr x 4/thread = exact cover.

typedef float f32x4 __attribute__((ext_vector_type(4)));

__global__ __launch_bounds__(256) void copy_f4x4(const f32x4* __restrict__ src,
                                                 f32x4* __restrict__ dst,
                                                 int n4) {
    int tid = blockIdx.x * blockDim.x + threadIdx.x;
    int stride = gridDim.x * blockDim.x;           // 1,048,576
    int i0 = tid;
    int i1 = tid + stride;
    int i2 = tid + 2 * stride;
    int i3 = tid + 3 * stride;
    // exact-fit fast path: all four in range (true for this problem size)
    if (i3 < n4) {
        f32x4 a = __builtin_nontemporal_load(&src[i0]);
        f32x4 b = __builtin_nontemporal_load(&src[i1]);
        f32x4 c = __builtin_nontemporal_load(&src[i2]);
        f32x4 d = __builtin_nontemporal_load(&src[i3]);
        __builtin_nontemporal_store(a, &dst[i0]);
        __builtin_nontemporal_store(b, &dst[i1]);
        __builtin_nontemporal_store(c, &dst[i2]);
        __builtin_nontemporal_store(d, &dst[i3]);
    } else {
        for (int i = i0; i < n4; i += stride) {
            f32x4 v = __builtin_nontemporal_load(&src[i]);
            __builtin_nontemporal_store(v, &dst[i]);
        }
    }
}

extern "C" void kernel_launch(void* const* d_in, const int* in_sizes, int n_in,
                              void* d_out, int out_size, void* d_ws, size_t ws_size,
                              hipStream_t stream) {
    const f32x4* rho = (const f32x4*)d_in[0];    // (N, DIM) fp32, 16B-aligned
    f32x4* out = (f32x4*)d_out;

    int n4 = out_size / 4;                       // 4,194,304
    int block = 256;
    int grid = (n4 + 4 * block - 1) / (4 * block);  // 4096
    copy_f4x4<<<grid, block, 0, stream>>>(rho, out, n4);
}

// Round 5
// 110.907 us; speedup vs baseline: 1.0924x; 1.0924x over previous
//
#include <hip/hip_runtime.h>

// HilbertSchmidtVQ — straight-through estimator forward pass.
//
// reference: out = rho_flat + (quantized - stop_gradient(quantized))
// Forward value == rho_flat bitwise (quantized cancels itself exactly);
// the argmin/gather over the codebook only affects gradients, which this
// single-output forward bench never evaluates. Optimal kernel = 64 MiB
// fp32 copy: 128 MiB HBM traffic, ~20 us at the chip's ~6.5 TB/s
// streaming rate (measured via the harness's own 268 MB fills @ 41 us).
//
// History: R1 SDMA memcpy 115.7 us; R2 this kernel 111.7 us; R4
// nontemporal+MLP variant 121.2 us. Spread ~= harness noise; dur_us is
// dominated by ~90-100 us of fixed harness stream work (256 MiB 0xAA
// poisons top every profile). Reverting to the best-measured, simplest
// version — further copy tuning is unmeasurable below the 41 us fill
// floor. nt stores appeared to HURT (bypass L2 write path), avoid.

__global__ __launch_bounds__(256) void copy_f4(const float4* __restrict__ src,
                                               float4* __restrict__ dst,
                                               int n4) {
    int i = blockIdx.x * blockDim.x + threadIdx.x;
    if (i < n4) dst[i] = src[i];
}

extern "C" void kernel_launch(void* const* d_in, const int* in_sizes, int n_in,
                              void* d_out, int out_size, void* d_ws, size_t ws_size,
                              hipStream_t stream) {
    const float4* rho = (const float4*)d_in[0];  // (N, DIM) fp32, 16B-aligned
    float4* out = (float4*)d_out;

    int n4 = out_size / 4;                       // 16,777,216 / 4 = 4,194,304
    int block = 256;
    int grid = (n4 + block - 1) / block;         // 16384
    copy_f4<<<grid, block, 0, stream>>>(rho, out, n4);
}